// Round 1
// baseline (333.110 us; speedup 1.0000x reference)
//
#include <hip/hip_runtime.h>

typedef __bf16 bf16x8 __attribute__((ext_vector_type(8)));
typedef float f32x4 __attribute__((ext_vector_type(4)));

constexpr int Bsz = 16;
constexpr int Nsz = 1024;
constexpr int Dsz = 256;
constexpr int Hsz = 4;
constexpr int HFsz = 256;
constexpr int BN = Bsz * Nsz;

__device__ __forceinline__ unsigned f2bf(float f) {   // RNE fp32->bf16 (finite in)
    unsigned u = __float_as_uint(f);
    return (u + 0x7FFFu + ((u >> 16) & 1u)) >> 16;
}

// ---------------------------------------------------------------------------
// Kernel 0: WbT[c][d] = bf16(W[d][c])  (transpose-convert, 256x256)
// ---------------------------------------------------------------------------
__global__ __launch_bounds__(256) void wcvt(const float* __restrict__ Wm,
                                            unsigned short* __restrict__ WbT) {
    const int t = threadIdx.x;
    const int c = blockIdx.x * 4 + (t >> 6);
    const int d0 = (t & 63) * 4;
    const float v0 = Wm[(size_t)(d0 + 0) * HFsz + c];
    const float v1 = Wm[(size_t)(d0 + 1) * HFsz + c];
    const float v2 = Wm[(size_t)(d0 + 2) * HFsz + c];
    const float v3 = Wm[(size_t)(d0 + 3) * HFsz + c];
    uint2 pk;
    pk.x = f2bf(v0) | (f2bf(v1) << 16);
    pk.y = f2bf(v2) | (f2bf(v3) << 16);
    *(uint2*)&WbT[(size_t)c * Dsz + d0] = pk;   // coalesced 512B/wave
}

// ---------------------------------------------------------------------------
// Kernel 1: hT = bf16(x @ W)^T via MFMA + fused e_src/e_dst (fp32 dots).
// (unchanged — verified correct, ~10 us)
// ---------------------------------------------------------------------------
__global__ __launch_bounds__(256) void gat_h_e3(
    const float* __restrict__ x,              // [BN][D]
    const unsigned short* __restrict__ WbT,   // [HF][D] bf16
    const float* __restrict__ a_src,          // [HF]
    const float* __restrict__ a_dst,          // [HF]
    unsigned short* __restrict__ hT,          // [B][HF][N] bf16
    float* __restrict__ esrcT,                // [B][H][N]
    float* __restrict__ edstT)                // [B][H][N]
{
    const int n0g = blockIdx.x * 32, b = n0g >> 10, n0 = n0g & 1023;
    const int t = threadIdx.x, lane = t & 63, w = t >> 6;
    const int m = lane & 15, q = lane >> 4;

    __shared__ alignas(16) unsigned short Lds[4 * 64 * 40];  // 10240 hw = 20 KB

    // ---- stage x -> bf16 xs (coalesced float4 reads) ----
    const float4* x4 = (const float4*)(x + (size_t)n0g * Dsz);
#pragma unroll
    for (int i = 0; i < 8; ++i) {
        const int f = t + 256 * i;             // 2048 float4 total
        const int row = f >> 6, d4 = (f & 63) * 4;
        const float4 xv = x4[f];
        uint2 pk;
        pk.x = f2bf(xv.x) | (f2bf(xv.y) << 16);
        pk.y = f2bf(xv.z) | (f2bf(xv.w) << 16);
        *(uint2*)&Lds[row * 264 + d4] = pk;
    }
    __syncthreads();

    const unsigned short* Ab = WbT + (size_t)(w * 64 + m) * Dsz + q * 8;
    f32x4 acc[4][2];
#pragma unroll
    for (int ht = 0; ht < 4; ++ht)
#pragma unroll
        for (int nt = 0; nt < 2; ++nt) acc[ht][nt] = (f32x4){0.f, 0.f, 0.f, 0.f};

#pragma unroll
    for (int kk = 0; kk < 8; ++kk) {
        const int k0 = kk * 32;
        const bf16x8 bfr0 = *(const bf16x8*)&Lds[(0 * 16 + m) * 264 + k0 + q * 8];
        const bf16x8 bfr1 = *(const bf16x8*)&Lds[(1 * 16 + m) * 264 + k0 + q * 8];
#pragma unroll
        for (int ht = 0; ht < 4; ++ht) {
            const bf16x8 afr = *(const bf16x8*)&Ab[ht * 16 * Dsz + k0];
            acc[ht][0] = __builtin_amdgcn_mfma_f32_16x16x32_bf16(afr, bfr0, acc[ht][0], 0, 0, 0);
            acc[ht][1] = __builtin_amdgcn_mfma_f32_16x16x32_bf16(afr, bfr1, acc[ht][1], 0, 0, 0);
        }
    }

    // ---- e_src/e_dst dots (head w = this wave's 64 hf cols) ----
    float ps0 = 0.f, ps1 = 0.f, pd0 = 0.f, pd1 = 0.f;
#pragma unroll
    for (int ht = 0; ht < 4; ++ht)
#pragma unroll
        for (int r = 0; r < 4; ++r) {
            const float as = a_src[w * 64 + ht * 16 + q * 4 + r];
            const float ad = a_dst[w * 64 + ht * 16 + q * 4 + r];
            ps0 += acc[ht][0][r] * as;  ps1 += acc[ht][1][r] * as;
            pd0 += acc[ht][0][r] * ad;  pd1 += acc[ht][1][r] * ad;
        }
    ps0 += __shfl_xor(ps0, 16, 64); ps0 += __shfl_xor(ps0, 32, 64);
    ps1 += __shfl_xor(ps1, 16, 64); ps1 += __shfl_xor(ps1, 32, 64);
    pd0 += __shfl_xor(pd0, 16, 64); pd0 += __shfl_xor(pd0, 32, 64);
    pd1 += __shfl_xor(pd1, 16, 64); pd1 += __shfl_xor(pd1, 32, 64);
    if (q == 0) {
        const size_t eb = (size_t)(b * Hsz + w) * Nsz + n0;
        esrcT[eb + m] = ps0;  esrcT[eb + 16 + m] = ps1;
        edstT[eb + m] = pd0;  edstT[eb + 16 + m] = pd1;
    }

    __syncthreads();   // xs no longer needed; reuse LDS as hs[4][64][40]

    // ---- write acc -> hs bf16 (wave-private region), then coalesced hT ----
#pragma unroll
    for (int ht = 0; ht < 4; ++ht)
#pragma unroll
        for (int r = 0; r < 4; ++r) {
            const int hf = ht * 16 + q * 4 + r;
            Lds[w * 2560 + hf * 40 + m]      = (unsigned short)f2bf(acc[ht][0][r]);
            Lds[w * 2560 + hf * 40 + 16 + m] = (unsigned short)f2bf(acc[ht][1][r]);
        }
    // hs[w] written & read only by wave w -> no barrier (in-wave lgkmcnt order)
#pragma unroll
    for (int s = 0; s < 4; ++s) {
        const int hf = s * 16 + (lane >> 2), ck = lane & 3;
        const bf16x8 hv = *(const bf16x8*)&Lds[w * 2560 + hf * 40 + ck * 8];
        *(bf16x8*)&hT[(size_t)(b * HFsz + w * 64 + hf) * Nsz + n0 + ck * 8] = hv;
    }
}

// ---------------------------------------------------------------------------
// Kernel 2 (v5): j-split across 4 waves per block to double resident waves.
// Rationale: v4 was latency-bound (VALUBusy 24%, MfmaUtil 5%, HBM 8%) with a
// hard cap of 16 waves/CU (4096 blocks x 1 wave). No-max softmax means
// partial num/den over disjoint j-ranges combine by pure addition -> split
// the 16 j-tiles 4-ways across 4 waves (grid unchanged: same XCD mapping),
// giving 16384 waves = up to 32 waves/CU. Per-wave main loop identical to v4
// (wave-private P region, barrier-free, adj/es prefetched one tile ahead).
// Epilogue: LDS tree-combine of (num[16], den[4]) per lane, then 256-thread
// coalesced float4 stores. LDS = 20480 B exactly -> 8 blocks/CU;
// __launch_bounds__(256,8) holds the 64-VGPR budget v4 already fit.
// Secondary: e_src/e_dst pre-scaled by log2(e); raw v_exp_f32 (=2^x) drops
// one v_mul per element (LeakyReLU/mask commute with the positive scale).
// ---------------------------------------------------------------------------
__global__ __launch_bounds__(256, 8) void gat_attn5(
    const float* __restrict__ adj,          // [B][N][N]
    const unsigned short* __restrict__ hT,  // [B][HF][N] bf16
    const float* __restrict__ esrcT,        // [B][H][N]
    const float* __restrict__ edstT,        // [B][H][N]
    const float* __restrict__ bias,         // [HF]
    float* __restrict__ outp)               // [BN][HF]
{
    const int gid = blockIdx.x;
    const int b  = gid & 15;                 // xcd = gid%8 -> b%8 (adj locality)
    const int hw = (gid >> 4) & 3;           // head
    const int i0 = (gid >> 6) * 16;
    const int t = threadIdx.x;
    const int lane = t & 63, ws = t >> 6;    // ws = j-split index (4 waves)
    const int m = lane & 15, q = lane >> 4;

    // 20480 B: main loop uses [0,9216) as 4 wave-private P tiles [16][72] hw;
    // epilogue (after barrier) aliases the whole thing as float comb[4][64][20].
    __shared__ alignas(16) unsigned char smem[20480];
    unsigned short* Pw = (unsigned short*)smem + ws * 1152;   // [16][72] per wave

    const float* adjb = adj + (size_t)b * Nsz * Nsz + (size_t)i0 * Nsz;
    const float* esb  = esrcT + (size_t)(b * Hsz + hw) * Nsz;
    const float* edb  = edstT + (size_t)(b * Hsz + hw) * Nsz + i0;
    const unsigned short* hTb = hT + (size_t)(b * HFsz + hw * 64 + m) * Nsz + q * 8;

    constexpr float LOG2E = 1.44269504088896340736f;
    float edreg[16];
#pragma unroll
    for (int il = 0; il < 16; ++il) edreg[il] = edb[il] * LOG2E;  // broadcast

    // ones B-frag for the denominator row-sum MFMA
    bf16x8 ones;
#pragma unroll
    for (int i = 0; i < 8; ++i)
        ((unsigned short*)&ones)[i] = 0x3F80;   // bf16 1.0

    // this wave owns j-tiles [ws*4, ws*4+4)
    const int jbase = ws * 4;

    float aA[16], aB[16];
    float esA, esB;
#pragma unroll
    for (int il = 0; il < 16; ++il) aA[il] = adjb[(size_t)il * Nsz + jbase * 64 + lane];
    esA = esb[jbase * 64 + lane] * LOG2E;

    f32x4 acc[4];
#pragma unroll
    for (int nt = 0; nt < 4; ++nt) acc[nt] = (f32x4){0.f, 0.f, 0.f, 0.f};
    f32x4 acc5 = (f32x4){0.f, 0.f, 0.f, 0.f};

    auto body = [&](int jt, int jn, float (&ac)[16], float& esc,
                    float (&an)[16], float& esn) {
        const int j0 = jt * 64;
        // (1) bfrag loads first (L2-hot), consumed this iteration
        bf16x8 bfr[8];
#pragma unroll
        for (int kk = 0; kk < 2; ++kk)
#pragma unroll
            for (int nt = 0; nt < 4; ++nt)
                bfr[kk * 4 + nt] =
                    *(const bf16x8*)&hTb[(size_t)nt * 16 * Nsz + j0 + kk * 32];

        // (2) next-tile HBM prefetch (jn = byte-col of next tile, dummy on last)
#pragma unroll
        for (int il = 0; il < 16; ++il)
            an[il] = adjb[(size_t)il * Nsz + jn + lane];
        esn = esb[jn + lane] * LOG2E;

        // (3) exp chain -> wave-private P (bf16 trunc; num/den consistent)
#pragma unroll
        for (int il = 0; il < 16; ++il) {
            float v = edreg[il] + esc;            // already x log2(e)
            v = fmaxf(v, 0.2f * v);               // LeakyReLU (scale>0 commutes)
            float p;
            asm("v_exp_f32 %0, %1" : "=v"(p) : "v"(v));   // 2^v
            unsigned u = __float_as_uint(p);
            u = (ac[il] > 0.5f) ? u : 0u;
            Pw[il * 72 + lane] = (unsigned short)(u >> 16);
        }
        // (4) MFMA: 8 aggregation + 2 denominator (wave-private LDS, no barrier)
#pragma unroll
        for (int kk = 0; kk < 2; ++kk) {
            const bf16x8 afrag = *(const bf16x8*)&Pw[m * 72 + kk * 32 + q * 8];
#pragma unroll
            for (int nt = 0; nt < 4; ++nt)
                acc[nt] = __builtin_amdgcn_mfma_f32_16x16x32_bf16(
                    afrag, bfr[kk * 4 + nt], acc[nt], 0, 0, 0);
            acc5 = __builtin_amdgcn_mfma_f32_16x16x32_bf16(afrag, ones, acc5,
                                                           0, 0, 0);
        }
    };

    // 4 tiles, ping-pong registers (no rotates); last prefetch is a dummy reload
    body(jbase + 0, (jbase + 1) * 64, aA, esA, aB, esB);
    body(jbase + 1, (jbase + 2) * 64, aB, esB, aA, esA);
    body(jbase + 2, (jbase + 3) * 64, aA, esA, aB, esB);
    body(jbase + 3, (jbase + 3) * 64, aB, esB, aA, esA);

    // ---- combine partial num/den across the 4 j-split waves ----
    __syncthreads();                       // all P reads done -> safe to alias
    float* comb = (float*)smem;            // [4][64][20]
    {
        float* cw = comb + (ws * 64 + lane) * 20;
#pragma unroll
        for (int nt = 0; nt < 4; ++nt)
#pragma unroll
            for (int r = 0; r < 4; ++r) cw[nt * 4 + r] = acc[nt][r];
#pragma unroll
        for (int r = 0; r < 4; ++r) cw[16 + r] = acc5[r];   // den rows q*4+r (dup over m)
    }
    __syncthreads();

    // 256 threads -> one float4 of the 16x64 output tile each
    const int row = t >> 4, c4 = t & 15;       // col block c4: cols c4*4..c4*4+3
    const int rq = row >> 2, rr = row & 3;
    const int nt4 = (c4 >> 2) * 4;             // (c>>4)*4, same for all 4 cols
    const int mb = (c4 & 3) * 4;               // m of first col
    float n0 = 0.f, n1 = 0.f, n2 = 0.f, n3 = 0.f, den = 0.f;
#pragma unroll
    for (int w4 = 0; w4 < 4; ++w4) {
        const float* cb = comb + (w4 * 64 + rq * 16) * 20;
        den += cb[16 + rr];                    // m=0 copy
        n0 += cb[(mb + 0) * 20 + nt4 + rr];
        n1 += cb[(mb + 1) * 20 + nt4 + rr];
        n2 += cb[(mb + 2) * 20 + nt4 + rr];
        n3 += cb[(mb + 3) * 20 + nt4 + rr];
    }
    const float inv = 1.f / den;
    const float4 b4 = *(const float4*)&bias[hw * 64 + c4 * 4];
    float4 o;
    o.x = n0 * inv + b4.x;  o.y = n1 * inv + b4.y;
    o.z = n2 * inv + b4.z;  o.w = n3 * inv + b4.w;
    *(float4*)&outp[(size_t)(b * Nsz + i0 + row) * HFsz + hw * 64 + c4 * 4] = o;
}

// ---------------------------------------------------------------------------
extern "C" void kernel_launch(void* const* d_in, const int* in_sizes, int n_in,
                              void* d_out, int out_size, void* d_ws, size_t ws_size,
                              hipStream_t stream) {
    const float* x     = (const float*)d_in[0];
    const float* adj   = (const float*)d_in[1];
    const float* Wm    = (const float*)d_in[2];
    const float* a_src = (const float*)d_in[3];
    const float* a_dst = (const float*)d_in[4];
    const float* bias  = (const float*)d_in[5];
    float* outp = (float*)d_out;

    // ws: hT bf16 (8MB) | WbT bf16 (128KB) | esrcT (256KB) | edstT (256KB)
    unsigned short* hT  = (unsigned short*)d_ws;
    unsigned short* WbT = hT + (size_t)BN * HFsz;
    float* esrcT = (float*)(WbT + (size_t)HFsz * Dsz);
    float* edstT = esrcT + (size_t)Bsz * Hsz * Nsz;

    wcvt<<<dim3(64), dim3(256), 0, stream>>>(Wm, WbT);
    gat_h_e3<<<dim3(BN / 32), dim3(256), 0, stream>>>(x, WbT, a_src, a_dst,
                                                      hT, esrcT, edstT);
    gat_attn5<<<dim3(4096), dim3(256), 0, stream>>>(adj, hT, esrcT, edstT,
                                                    bias, outp);
}

// Round 3
// 212.705 us; speedup vs baseline: 1.5661x; 1.5661x over previous
//
#include <hip/hip_runtime.h>

typedef __bf16 bf16x8 __attribute__((ext_vector_type(8)));
typedef float f32x4 __attribute__((ext_vector_type(4)));

constexpr int Bsz = 16;
constexpr int Nsz = 1024;
constexpr int Dsz = 256;
constexpr int Hsz = 4;
constexpr int HFsz = 256;
constexpr int BN = Bsz * Nsz;
constexpr float LOG2E = 1.44269504088896340736f;

__device__ __forceinline__ unsigned f2bf(float f) {   // RNE fp32->bf16 (finite in)
    unsigned u = __float_as_uint(f);
    return (u + 0x7FFFu + ((u >> 16) & 1u)) >> 16;
}

// ---------------------------------------------------------------------------
// Kernel 0: WbT[c][d] = bf16(W[d][c])  (transpose-convert, 256x256)
// ---------------------------------------------------------------------------
__global__ __launch_bounds__(256) void wcvt(const float* __restrict__ Wm,
                                            unsigned short* __restrict__ WbT) {
    const int t = threadIdx.x;
    const int c = blockIdx.x * 4 + (t >> 6);
    const int d0 = (t & 63) * 4;
    const float v0 = Wm[(size_t)(d0 + 0) * HFsz + c];
    const float v1 = Wm[(size_t)(d0 + 1) * HFsz + c];
    const float v2 = Wm[(size_t)(d0 + 2) * HFsz + c];
    const float v3 = Wm[(size_t)(d0 + 3) * HFsz + c];
    uint2 pk;
    pk.x = f2bf(v0) | (f2bf(v1) << 16);
    pk.y = f2bf(v2) | (f2bf(v3) << 16);
    *(uint2*)&WbT[(size_t)c * Dsz + d0] = pk;   // coalesced 512B/wave
}

// ---------------------------------------------------------------------------
// Kernel 1: hT = bf16(x @ W)^T via MFMA + fused e_src/e_dst (fp32 dots).
// e_src/e_dst are stored PRE-SCALED by log2(e) so the attn kernel can use
// raw v_exp_f32 (2^x) with no runtime multiply.
// ---------------------------------------------------------------------------
__global__ __launch_bounds__(256) void gat_h_e3(
    const float* __restrict__ x,              // [BN][D]
    const unsigned short* __restrict__ WbT,   // [HF][D] bf16
    const float* __restrict__ a_src,          // [HF]
    const float* __restrict__ a_dst,          // [HF]
    unsigned short* __restrict__ hT,          // [B][HF][N] bf16
    float* __restrict__ esrcT,                // [B][H][N]  (x log2e)
    float* __restrict__ edstT)                // [B][H][N]  (x log2e)
{
    const int n0g = blockIdx.x * 32, b = n0g >> 10, n0 = n0g & 1023;
    const int t = threadIdx.x, lane = t & 63, w = t >> 6;
    const int m = lane & 15, q = lane >> 4;

    __shared__ alignas(16) unsigned short Lds[4 * 64 * 40];  // 10240 hw = 20 KB

    // ---- stage x -> bf16 xs (coalesced float4 reads) ----
    const float4* x4 = (const float4*)(x + (size_t)n0g * Dsz);
#pragma unroll
    for (int i = 0; i < 8; ++i) {
        const int f = t + 256 * i;             // 2048 float4 total
        const int row = f >> 6, d4 = (f & 63) * 4;
        const float4 xv = x4[f];
        uint2 pk;
        pk.x = f2bf(xv.x) | (f2bf(xv.y) << 16);
        pk.y = f2bf(xv.z) | (f2bf(xv.w) << 16);
        *(uint2*)&Lds[row * 264 + d4] = pk;
    }
    __syncthreads();

    const unsigned short* Ab = WbT + (size_t)(w * 64 + m) * Dsz + q * 8;
    f32x4 acc[4][2];
#pragma unroll
    for (int ht = 0; ht < 4; ++ht)
#pragma unroll
        for (int nt = 0; nt < 2; ++nt) acc[ht][nt] = (f32x4){0.f, 0.f, 0.f, 0.f};

#pragma unroll
    for (int kk = 0; kk < 8; ++kk) {
        const int k0 = kk * 32;
        const bf16x8 bfr0 = *(const bf16x8*)&Lds[(0 * 16 + m) * 264 + k0 + q * 8];
        const bf16x8 bfr1 = *(const bf16x8*)&Lds[(1 * 16 + m) * 264 + k0 + q * 8];
#pragma unroll
        for (int ht = 0; ht < 4; ++ht) {
            const bf16x8 afr = *(const bf16x8*)&Ab[ht * 16 * Dsz + k0];
            acc[ht][0] = __builtin_amdgcn_mfma_f32_16x16x32_bf16(afr, bfr0, acc[ht][0], 0, 0, 0);
            acc[ht][1] = __builtin_amdgcn_mfma_f32_16x16x32_bf16(afr, bfr1, acc[ht][1], 0, 0, 0);
        }
    }

    // ---- e_src/e_dst dots (head w = this wave's 64 hf cols) ----
    float ps0 = 0.f, ps1 = 0.f, pd0 = 0.f, pd1 = 0.f;
#pragma unroll
    for (int ht = 0; ht < 4; ++ht)
#pragma unroll
        for (int r = 0; r < 4; ++r) {
            const float as = a_src[w * 64 + ht * 16 + q * 4 + r];
            const float ad = a_dst[w * 64 + ht * 16 + q * 4 + r];
            ps0 += acc[ht][0][r] * as;  ps1 += acc[ht][1][r] * as;
            pd0 += acc[ht][0][r] * ad;  pd1 += acc[ht][1][r] * ad;
        }
    ps0 += __shfl_xor(ps0, 16, 64); ps0 += __shfl_xor(ps0, 32, 64);
    ps1 += __shfl_xor(ps1, 16, 64); ps1 += __shfl_xor(ps1, 32, 64);
    pd0 += __shfl_xor(pd0, 16, 64); pd0 += __shfl_xor(pd0, 32, 64);
    pd1 += __shfl_xor(pd1, 16, 64); pd1 += __shfl_xor(pd1, 32, 64);
    if (q == 0) {
        const size_t eb = (size_t)(b * Hsz + w) * Nsz + n0;
        esrcT[eb + m]      = ps0 * LOG2E;  esrcT[eb + 16 + m] = ps1 * LOG2E;
        edstT[eb + m]      = pd0 * LOG2E;  edstT[eb + 16 + m] = pd1 * LOG2E;
    }

    __syncthreads();   // xs no longer needed; reuse LDS as hs[4][64][40]

    // ---- write acc -> hs bf16 (wave-private region), then coalesced hT ----
#pragma unroll
    for (int ht = 0; ht < 4; ++ht)
#pragma unroll
        for (int r = 0; r < 4; ++r) {
            const int hf = ht * 16 + q * 4 + r;
            Lds[w * 2560 + hf * 40 + m]      = (unsigned short)f2bf(acc[ht][0][r]);
            Lds[w * 2560 + hf * 40 + 16 + m] = (unsigned short)f2bf(acc[ht][1][r]);
        }
    // hs[w] written & read only by wave w -> no barrier (in-wave lgkmcnt order)
#pragma unroll
    for (int s = 0; s < 4; ++s) {
        const int hf = s * 16 + (lane >> 2), ck = lane & 3;
        const bf16x8 hv = *(const bf16x8*)&Lds[w * 2560 + hf * 40 + ck * 8];
        *(bf16x8*)&hT[(size_t)(b * HFsz + w * 64 + hf) * Nsz + n0 + ck * 8] = hv;
    }
}

// ---------------------------------------------------------------------------
// Kernel 2 (v6): fragment-direct P, 4-wave j-split, lean registers.
// R1 post-mortem: launch_bounds(256,8) = 64-reg unified cap -> massive scratch
// spills (FETCH 200MB / WRITE 328MB). v6 removes the register demand instead
// of the occupancy: each lane computes P directly in the MFMA A-fragment
// layout (row i0+m, cols j0+kk*32+q*8+0..7), so:
//   - edreg[16] -> one scalar ed_s
//   - adj/es ping-pong arrays (33 regs) -> transient float4 loads
//   - LDS P tile + its bank conflicts + ds round-trip -> gone entirely
// launch_bounds(256,6): 85-reg unified cap, est. demand ~75 -> no spills,
// 6 blocks/CU = 24 waves/CU (vs v4's 16). #pragma unroll 1 on the tile loop
// keeps transient pressure bounded; TLP (not unrolling) hides latency.
// Epilogue combine is v5's (harness-verified) verbatim.
// ---------------------------------------------------------------------------
__device__ __forceinline__ unsigned pexp2(float ed, float e0, float e1,
                                          float a0, float a1) {
    float v0 = ed + e0, v1 = ed + e1;          // already x log2e
    v0 = fmaxf(v0, 0.2f * v0);                 // LeakyReLU (scale>0 commutes)
    v1 = fmaxf(v1, 0.2f * v1);
    float p0, p1;
    asm("v_exp_f32 %0, %1" : "=v"(p0) : "v"(v0));   // 2^v
    asm("v_exp_f32 %0, %1" : "=v"(p1) : "v"(v1));
    unsigned u0 = __float_as_uint(p0), u1 = __float_as_uint(p1);
    u0 = (a0 > 0.5f) ? u0 : 0u;                // mask
    u1 = (a1 > 0.5f) ? u1 : 0u;
    return (u0 >> 16) | (u1 & 0xFFFF0000u);    // 2x bf16 trunc, packed
}

__global__ __launch_bounds__(256, 6) void gat_attn6(
    const float* __restrict__ adj,          // [B][N][N]
    const unsigned short* __restrict__ hT,  // [B][HF][N] bf16
    const float* __restrict__ esrcT,        // [B][H][N] (x log2e)
    const float* __restrict__ edstT,        // [B][H][N] (x log2e)
    const float* __restrict__ bias,         // [HF]
    float* __restrict__ outp)               // [BN][HF]
{
    const int gid = blockIdx.x;
    const int b  = gid & 15;                 // xcd = gid%8 -> b%8 (adj locality)
    const int hw = (gid >> 4) & 3;           // head
    const int i0 = (gid >> 6) * 16;
    const int t = threadIdx.x;
    const int lane = t & 63, ws = t >> 6;    // ws = j-split index (4 waves)
    const int m = lane & 15, q = lane >> 4;

    __shared__ alignas(16) float comb[4 * 64 * 20];   // 20480 B (epilogue only)

    const float* adjr = adj + (size_t)b * Nsz * Nsz + (size_t)(i0 + m) * Nsz;
    const float* esb  = esrcT + (size_t)(b * Hsz + hw) * Nsz;
    const float ed_s  = edstT[(size_t)(b * Hsz + hw) * Nsz + i0 + m];
    const unsigned short* hTb = hT + (size_t)(b * HFsz + hw * 64 + m) * Nsz + q * 8;

    bf16x8 ones;                              // denominator row-sum B-frag
#pragma unroll
    for (int i = 0; i < 8; ++i)
        ((unsigned short*)&ones)[i] = 0x3F80; // bf16 1.0

    f32x4 acc[4];
#pragma unroll
    for (int nt = 0; nt < 4; ++nt) acc[nt] = (f32x4){0.f, 0.f, 0.f, 0.f};
    f32x4 acc5 = (f32x4){0.f, 0.f, 0.f, 0.f};

#pragma unroll 1
    for (int jt = 0; jt < 4; ++jt) {          // this wave's 4 j-tiles
        const int j0 = (ws * 4 + jt) * 64;
#pragma unroll
        for (int kk = 0; kk < 2; ++kk) {
            const int jc = j0 + kk * 32 + q * 8;
            // adj row (i0+m), 8 cols; es same 8 cols (L1-broadcast over m)
            const float4 a0 = *(const float4*)&adjr[jc];
            const float4 a1 = *(const float4*)&adjr[jc + 4];
            const float4 e0 = *(const float4*)&esb[jc];
            const float4 e1 = *(const float4*)&esb[jc + 4];
            bf16x8 bfr[4];
#pragma unroll
            for (int nt = 0; nt < 4; ++nt)
                bfr[nt] = *(const bf16x8*)&hTb[(size_t)nt * 16 * Nsz + j0 + kk * 32];

            union { unsigned u[4]; bf16x8 v; } af;
            af.u[0] = pexp2(ed_s, e0.x, e0.y, a0.x, a0.y);
            af.u[1] = pexp2(ed_s, e0.z, e0.w, a0.z, a0.w);
            af.u[2] = pexp2(ed_s, e1.x, e1.y, a1.x, a1.y);
            af.u[3] = pexp2(ed_s, e1.z, e1.w, a1.z, a1.w);

#pragma unroll
            for (int nt = 0; nt < 4; ++nt)
                acc[nt] = __builtin_amdgcn_mfma_f32_16x16x32_bf16(
                    af.v, bfr[nt], acc[nt], 0, 0, 0);
            acc5 = __builtin_amdgcn_mfma_f32_16x16x32_bf16(af.v, ones, acc5,
                                                           0, 0, 0);
        }
    }

    // ---- combine partial num/den across the 4 j-split waves (v5-verified) ----
    __syncthreads();
    {
        float* cw = comb + (ws * 64 + lane) * 20;
#pragma unroll
        for (int nt = 0; nt < 4; ++nt)
#pragma unroll
            for (int r = 0; r < 4; ++r) cw[nt * 4 + r] = acc[nt][r];
#pragma unroll
        for (int r = 0; r < 4; ++r) cw[16 + r] = acc5[r];   // den rows q*4+r
    }
    __syncthreads();

    // 256 threads -> one float4 of the 16x64 output tile each
    const int row = t >> 4, c4 = t & 15;       // col block c4: cols c4*4..c4*4+3
    const int rq = row >> 2, rr = row & 3;
    const int nt4 = (c4 >> 2) * 4;
    const int mb = (c4 & 3) * 4;
    float n0 = 0.f, n1 = 0.f, n2 = 0.f, n3 = 0.f, den = 0.f;
#pragma unroll
    for (int w4 = 0; w4 < 4; ++w4) {
        const float* cb = comb + (w4 * 64 + rq * 16) * 20;
        den += cb[16 + rr];                    // m=0 copy
        n0 += cb[(mb + 0) * 20 + nt4 + rr];
        n1 += cb[(mb + 1) * 20 + nt4 + rr];
        n2 += cb[(mb + 2) * 20 + nt4 + rr];
        n3 += cb[(mb + 3) * 20 + nt4 + rr];
    }
    const float inv = 1.f / den;
    const float4 b4 = *(const float4*)&bias[hw * 64 + c4 * 4];
    float4 o;
    o.x = n0 * inv + b4.x;  o.y = n1 * inv + b4.y;
    o.z = n2 * inv + b4.z;  o.w = n3 * inv + b4.w;
    *(float4*)&outp[(size_t)(b * Nsz + i0 + row) * HFsz + hw * 64 + c4 * 4] = o;
}

// ---------------------------------------------------------------------------
extern "C" void kernel_launch(void* const* d_in, const int* in_sizes, int n_in,
                              void* d_out, int out_size, void* d_ws, size_t ws_size,
                              hipStream_t stream) {
    const float* x     = (const float*)d_in[0];
    const float* adj   = (const float*)d_in[1];
    const float* Wm    = (const float*)d_in[2];
    const float* a_src = (const float*)d_in[3];
    const float* a_dst = (const float*)d_in[4];
    const float* bias  = (const float*)d_in[5];
    float* outp = (float*)d_out;

    // ws: hT bf16 (8MB) | WbT bf16 (128KB) | esrcT (256KB) | edstT (256KB)
    unsigned short* hT  = (unsigned short*)d_ws;
    unsigned short* WbT = hT + (size_t)BN * HFsz;
    float* esrcT = (float*)(WbT + (size_t)HFsz * Dsz);
    float* edstT = esrcT + (size_t)Bsz * Hsz * Nsz;

    wcvt<<<dim3(64), dim3(256), 0, stream>>>(Wm, WbT);
    gat_h_e3<<<dim3(BN / 32), dim3(256), 0, stream>>>(x, WbT, a_src, a_dst,
                                                      hT, esrcT, edstT);
    gat_attn6<<<dim3(4096), dim3(256), 0, stream>>>(adj, hT, esrcT, edstT,
                                                    bias, outp);
}

// Round 7
// 195.089 us; speedup vs baseline: 1.7075x; 1.0903x over previous
//
#include <hip/hip_runtime.h>

typedef __bf16 bf16x8 __attribute__((ext_vector_type(8)));
typedef float f32x4 __attribute__((ext_vector_type(4)));

constexpr int Bsz = 16;
constexpr int Nsz = 1024;
constexpr int Dsz = 256;
constexpr int Hsz = 4;
constexpr int HFsz = 256;
constexpr int BN = Bsz * Nsz;
constexpr float LOG2E = 1.44269504088896340736f;

__device__ __forceinline__ unsigned f2bf(float f) {   // RNE fp32->bf16 (finite in)
    unsigned u = __float_as_uint(f);
    return (u + 0x7FFFu + ((u >> 16) & 1u)) >> 16;
}

// ---------------------------------------------------------------------------
// Kernel 0: WbT[c][d] = bf16(W[d][c])  (transpose-convert, 256x256)
// ---------------------------------------------------------------------------
__global__ __launch_bounds__(256) void wcvt(const float* __restrict__ Wm,
                                            unsigned short* __restrict__ WbT) {
    const int t = threadIdx.x;
    const int c = blockIdx.x * 4 + (t >> 6);
    const int d0 = (t & 63) * 4;
    const float v0 = Wm[(size_t)(d0 + 0) * HFsz + c];
    const float v1 = Wm[(size_t)(d0 + 1) * HFsz + c];
    const float v2 = Wm[(size_t)(d0 + 2) * HFsz + c];
    const float v3 = Wm[(size_t)(d0 + 3) * HFsz + c];
    uint2 pk;
    pk.x = f2bf(v0) | (f2bf(v1) << 16);
    pk.y = f2bf(v2) | (f2bf(v3) << 16);
    *(uint2*)&WbT[(size_t)c * Dsz + d0] = pk;   // coalesced 512B/wave
}

// ---------------------------------------------------------------------------
// Kernel 1: hT = bf16(x @ W)^T via MFMA + fused e_src/e_dst (fp32 dots).
// e_src/e_dst stored PRE-SCALED by log2(e) -> attn uses raw v_exp_f32 (2^x).
// (unchanged, verified)
// ---------------------------------------------------------------------------
__global__ __launch_bounds__(256) void gat_h_e3(
    const float* __restrict__ x,              // [BN][D]
    const unsigned short* __restrict__ WbT,   // [HF][D] bf16
    const float* __restrict__ a_src,          // [HF]
    const float* __restrict__ a_dst,          // [HF]
    unsigned short* __restrict__ hT,          // [B][HF][N] bf16
    float* __restrict__ esrcT,                // [B][H][N]  (x log2e)
    float* __restrict__ edstT)                // [B][H][N]  (x log2e)
{
    const int n0g = blockIdx.x * 32, b = n0g >> 10, n0 = n0g & 1023;
    const int t = threadIdx.x, lane = t & 63, w = t >> 6;
    const int m = lane & 15, q = lane >> 4;

    __shared__ alignas(16) unsigned short Lds[4 * 64 * 40];  // 10240 hw = 20 KB

    // ---- stage x -> bf16 xs (coalesced float4 reads) ----
    const float4* x4 = (const float4*)(x + (size_t)n0g * Dsz);
#pragma unroll
    for (int i = 0; i < 8; ++i) {
        const int f = t + 256 * i;             // 2048 float4 total
        const int row = f >> 6, d4 = (f & 63) * 4;
        const float4 xv = x4[f];
        uint2 pk;
        pk.x = f2bf(xv.x) | (f2bf(xv.y) << 16);
        pk.y = f2bf(xv.z) | (f2bf(xv.w) << 16);
        *(uint2*)&Lds[row * 264 + d4] = pk;
    }
    __syncthreads();

    const unsigned short* Ab = WbT + (size_t)(w * 64 + m) * Dsz + q * 8;
    f32x4 acc[4][2];
#pragma unroll
    for (int ht = 0; ht < 4; ++ht)
#pragma unroll
        for (int nt = 0; nt < 2; ++nt) acc[ht][nt] = (f32x4){0.f, 0.f, 0.f, 0.f};

#pragma unroll
    for (int kk = 0; kk < 8; ++kk) {
        const int k0 = kk * 32;
        const bf16x8 bfr0 = *(const bf16x8*)&Lds[(0 * 16 + m) * 264 + k0 + q * 8];
        const bf16x8 bfr1 = *(const bf16x8*)&Lds[(1 * 16 + m) * 264 + k0 + q * 8];
#pragma unroll
        for (int ht = 0; ht < 4; ++ht) {
            const bf16x8 afr = *(const bf16x8*)&Ab[ht * 16 * Dsz + k0];
            acc[ht][0] = __builtin_amdgcn_mfma_f32_16x16x32_bf16(afr, bfr0, acc[ht][0], 0, 0, 0);
            acc[ht][1] = __builtin_amdgcn_mfma_f32_16x16x32_bf16(afr, bfr1, acc[ht][1], 0, 0, 0);
        }
    }

    // ---- e_src/e_dst dots (head w = this wave's 64 hf cols) ----
    float ps0 = 0.f, ps1 = 0.f, pd0 = 0.f, pd1 = 0.f;
#pragma unroll
    for (int ht = 0; ht < 4; ++ht)
#pragma unroll
        for (int r = 0; r < 4; ++r) {
            const float as = a_src[w * 64 + ht * 16 + q * 4 + r];
            const float ad = a_dst[w * 64 + ht * 16 + q * 4 + r];
            ps0 += acc[ht][0][r] * as;  ps1 += acc[ht][1][r] * as;
            pd0 += acc[ht][0][r] * ad;  pd1 += acc[ht][1][r] * ad;
        }
    ps0 += __shfl_xor(ps0, 16, 64); ps0 += __shfl_xor(ps0, 32, 64);
    ps1 += __shfl_xor(ps1, 16, 64); ps1 += __shfl_xor(ps1, 32, 64);
    pd0 += __shfl_xor(pd0, 16, 64); pd0 += __shfl_xor(pd0, 32, 64);
    pd1 += __shfl_xor(pd1, 16, 64); pd1 += __shfl_xor(pd1, 32, 64);
    if (q == 0) {
        const size_t eb = (size_t)(b * Hsz + w) * Nsz + n0;
        esrcT[eb + m]      = ps0 * LOG2E;  esrcT[eb + 16 + m] = ps1 * LOG2E;
        edstT[eb + m]      = pd0 * LOG2E;  edstT[eb + 16 + m] = pd1 * LOG2E;
    }

    __syncthreads();   // xs no longer needed; reuse LDS as hs[4][64][40]

    // ---- write acc -> hs bf16 (wave-private region), then coalesced hT ----
#pragma unroll
    for (int ht = 0; ht < 4; ++ht)
#pragma unroll
        for (int r = 0; r < 4; ++r) {
            const int hf = ht * 16 + q * 4 + r;
            Lds[w * 2560 + hf * 40 + m]      = (unsigned short)f2bf(acc[ht][0][r]);
            Lds[w * 2560 + hf * 40 + 16 + m] = (unsigned short)f2bf(acc[ht][1][r]);
        }
    // hs[w] written & read only by wave w -> no barrier (in-wave lgkmcnt order)
#pragma unroll
    for (int s = 0; s < 4; ++s) {
        const int hf = s * 16 + (lane >> 2), ck = lane & 3;
        const bf16x8 hv = *(const bf16x8*)&Lds[w * 2560 + hf * 40 + ck * 8];
        *(bf16x8*)&hT[(size_t)(b * HFsz + w * 64 + hf) * Nsz + n0 + ck * 8] = hv;
    }
}

// ---------------------------------------------------------------------------
// Kernel 2 (v7): adj shared across heads via LDS double-buffer prefetch.
// R3 post-mortem: v6 (no prefetch) was latency-serial per iteration (VALU 17%,
// MFMA 3.8%, HBM 6.5% -- everything idle); v4's explicit prefetch was the
// thing that made 83us possible. v7: block = 512 thr = 8 waves = (head hh,
// j-half jh) per (b, i-tile16). The 4 head-waves of a j-half share ONE adj
// tile (16x64 f32) staged in LDS, double-buffered, cooperatively prefetched
// one tile ahead (1 float4/lane issue cost; HBM/L3 latency hides under a
// full tile of compute). adj is now read ONCE instead of once per head, and
// the critical-path access is a ~120cy LDS read. 1024 blocks x 8 waves =
// 24 waves/CU at launch_bounds(512,6) (85-reg cap; est demand ~75).
// Same-b blocks map to one XCD (gid&15 -> gid%8 const) -> hT[b] L2-resident.
// Partial num/den (no-max softmax) combine by addition in the verified comb
// epilogue, extended to 8 waves (2 j-halves x 4 heads).
// ---------------------------------------------------------------------------
__device__ __forceinline__ unsigned pexp2(float ed, float e0, float e1,
                                          float a0, float a1) {
    float v0 = ed + e0, v1 = ed + e1;          // already x log2e
    v0 = fmaxf(v0, 0.2f * v0);                 // LeakyReLU (scale>0 commutes)
    v1 = fmaxf(v1, 0.2f * v1);
    float p0, p1;
    asm("v_exp_f32 %0, %1" : "=v"(p0) : "v"(v0));   // 2^v
    asm("v_exp_f32 %0, %1" : "=v"(p1) : "v"(v1));
    unsigned u0 = __float_as_uint(p0), u1 = __float_as_uint(p1);
    u0 = (a0 > 0.5f) ? u0 : 0u;                // mask
    u1 = (a1 > 0.5f) ? u1 : 0u;
    return (u0 >> 16) | (u1 & 0xFFFF0000u);    // 2x bf16 trunc, packed
}

__global__ __launch_bounds__(512, 6) void gat_attn7(
    const float* __restrict__ adj,          // [B][N][N]
    const unsigned short* __restrict__ hT,  // [B][HF][N] bf16
    const float* __restrict__ esrcT,        // [B][H][N] (x log2e)
    const float* __restrict__ edstT,        // [B][H][N] (x log2e)
    const float* __restrict__ bias,         // [HF]
    float* __restrict__ outp)               // [BN][HF]
{
    const int gid = blockIdx.x;
    const int b  = gid & 15;                 // same-b -> same XCD (gid%8 const)
    const int i0 = (gid >> 4) * 16;
    const int t = threadIdx.x;
    const int lane = t & 63, ws = t >> 6;
    const int hh = ws & 3, jh = ws >> 2;     // head, j-half
    const int m = lane & 15, q = lane >> 4;

    // [0,17408): adj stage, 4 tiles of [16][68] f32 (jh*2+buf);
    // epilogue aliases all 40960 B as comb[8][64][20] f32.
    __shared__ alignas(16) float smem[10240];

    // stage role of this lane: row hh*4+q (4 rows/wave), col4 m
    const float* adjSg = adj + (size_t)b * Nsz * Nsz
                             + (size_t)(i0 + hh * 4 + q) * Nsz + m * 4;
    float* stW = &smem[(jh * 2) * 1088 + (hh * 4 + q) * 68 + m * 4];
    const float* stR = &smem[(jh * 2) * 1088 + m * 68];

    const float* esb = esrcT + (size_t)(b * Hsz + hh) * Nsz;
    const float ed_s = edstT[(size_t)(b * Hsz + hh) * Nsz + i0 + m];
    const unsigned short* hTb = hT + (size_t)(b * HFsz + hh * 64 + m) * Nsz + q * 8;
    const int jt0 = jh * 8;                  // this wave's first j-tile

    bf16x8 ones;                             // denominator row-sum B-frag
#pragma unroll
    for (int i = 0; i < 8; ++i)
        ((unsigned short*)&ones)[i] = 0x3F80;   // bf16 1.0

    f32x4 acc[4];
#pragma unroll
    for (int nt = 0; nt < 4; ++nt) acc[nt] = (f32x4){0.f, 0.f, 0.f, 0.f};
    f32x4 acc5 = (f32x4){0.f, 0.f, 0.f, 0.f};

    // prologue: stage tile 0 into buf 0
    {
        const float4 g = *(const float4*)&adjSg[jt0 * 64];
        *(float4*)&stW[0] = g;
    }
    __syncthreads();

#pragma unroll 1
    for (int jl = 0; jl < 8; ++jl) {
        const int buf = jl & 1;
        const int j0 = (jt0 + jl) * 64;

        // issue next-tile adj prefetch (consumed after the barrier below)
        float4 g;
        if (jl < 7) g = *(const float4*)&adjSg[(jt0 + jl + 1) * 64];

        const float* rd = stR + buf * 1088;
#pragma unroll
        for (int kk = 0; kk < 2; ++kk) {
            const int jc = j0 + kk * 32 + q * 8;
            const float4 a0 = *(const float4*)&rd[kk * 32 + q * 8];
            const float4 a1 = *(const float4*)&rd[kk * 32 + q * 8 + 4];
            const float4 e0 = *(const float4*)&esb[jc];
            const float4 e1 = *(const float4*)&esb[jc + 4];
            bf16x8 bfr[4];
#pragma unroll
            for (int nt = 0; nt < 4; ++nt)
                bfr[nt] = *(const bf16x8*)&hTb[(size_t)nt * 16 * Nsz + j0 + kk * 32];

            union { unsigned u[4]; bf16x8 v; } af;
            af.u[0] = pexp2(ed_s, e0.x, e0.y, a0.x, a0.y);
            af.u[1] = pexp2(ed_s, e0.z, e0.w, a0.z, a0.w);
            af.u[2] = pexp2(ed_s, e1.x, e1.y, a1.x, a1.y);
            af.u[3] = pexp2(ed_s, e1.z, e1.w, a1.z, a1.w);

#pragma unroll
            for (int nt = 0; nt < 4; ++nt)
                acc[nt] = __builtin_amdgcn_mfma_f32_16x16x32_bf16(
                    af.v, bfr[nt], acc[nt], 0, 0, 0);
            acc5 = __builtin_amdgcn_mfma_f32_16x16x32_bf16(af.v, ones, acc5,
                                                           0, 0, 0);
        }

        __syncthreads();                     // all reads of buf^1 (prev iter) done
        if (jl < 7) *(float4*)&stW[(buf ^ 1) * 1088] = g;
        __syncthreads();                     // stage visible before next compute
    }

    // ---- comb epilogue: 8 waves write partials, 512 threads reduce+store ----
    {
        float* cw = &smem[t * 20];           // (ws*64+lane)*20 == t*20
#pragma unroll
        for (int nt = 0; nt < 4; ++nt)
#pragma unroll
            for (int r = 0; r < 4; ++r) cw[nt * 4 + r] = acc[nt][r];
#pragma unroll
        for (int r = 0; r < 4; ++r) cw[16 + r] = acc5[r];   // den rows q*4+r
    }
    __syncthreads();

#pragma unroll
    for (int u = 0; u < 2; ++u) {
        const int idx = t * 2 + u;               // 1024 float4 cells
        const int row = idx >> 6, c4g = idx & 63;
        const int hh2 = c4g >> 4, c4l = c4g & 15;
        const int rq = row >> 2, rr = row & 3;
        const int nt4 = (c4l >> 2) * 4, mb = (c4l & 3) * 4;
        float n0 = 0.f, n1 = 0.f, n2 = 0.f, n3 = 0.f, den = 0.f;
#pragma unroll
        for (int j2 = 0; j2 < 2; ++j2) {         // sum the two j-halves
            const float* cb = &smem[((j2 * 4 + hh2) * 64 + rq * 16) * 20];
            den += cb[16 + rr];                  // m=0 copy
            n0 += cb[(mb + 0) * 20 + nt4 + rr];
            n1 += cb[(mb + 1) * 20 + nt4 + rr];
            n2 += cb[(mb + 2) * 20 + nt4 + rr];
            n3 += cb[(mb + 3) * 20 + nt4 + rr];
        }
        const float inv = 1.f / den;
        const float4 b4 = *(const float4*)&bias[hh2 * 64 + c4l * 4];
        float4 o;
        o.x = n0 * inv + b4.x;  o.y = n1 * inv + b4.y;
        o.z = n2 * inv + b4.z;  o.w = n3 * inv + b4.w;
        *(float4*)&outp[(size_t)(b * Nsz + i0 + row) * HFsz + c4g * 4] = o;
    }
}

// ---------------------------------------------------------------------------
extern "C" void kernel_launch(void* const* d_in, const int* in_sizes, int n_in,
                              void* d_out, int out_size, void* d_ws, size_t ws_size,
                              hipStream_t stream) {
    const float* x     = (const float*)d_in[0];
    const float* adj   = (const float*)d_in[1];
    const float* Wm    = (const float*)d_in[2];
    const float* a_src = (const float*)d_in[3];
    const float* a_dst = (const float*)d_in[4];
    const float* bias  = (const float*)d_in[5];
    float* outp = (float*)d_out;

    // ws: hT bf16 (8MB) | WbT bf16 (128KB) | esrcT (256KB) | edstT (256KB)
    unsigned short* hT  = (unsigned short*)d_ws;
    unsigned short* WbT = hT + (size_t)BN * HFsz;
    float* esrcT = (float*)(WbT + (size_t)HFsz * Dsz);
    float* edstT = esrcT + (size_t)Bsz * Hsz * Nsz;

    wcvt<<<dim3(64), dim3(256), 0, stream>>>(Wm, WbT);
    gat_h_e3<<<dim3(BN / 32), dim3(256), 0, stream>>>(x, WbT, a_src, a_dst,
                                                      hT, esrcT, edstT);
    gat_attn7<<<dim3(1024), dim3(512), 0, stream>>>(adj, hT, esrcT, edstT,
                                                    bias, outp);
}

// Round 9
// 192.091 us; speedup vs baseline: 1.7341x; 1.0156x over previous
//
#include <hip/hip_runtime.h>

typedef __bf16 bf16x8 __attribute__((ext_vector_type(8)));
typedef float f32x4 __attribute__((ext_vector_type(4)));

constexpr int Bsz = 16;
constexpr int Nsz = 1024;
constexpr int Dsz = 256;
constexpr int Hsz = 4;
constexpr int HFsz = 256;
constexpr int BN = Bsz * Nsz;
constexpr float LOG2E = 1.44269504088896340736f;

__device__ __forceinline__ unsigned f2bf(float f) {   // RNE fp32->bf16 (finite in)
    unsigned u = __float_as_uint(f);
    return (u + 0x7FFFu + ((u >> 16) & 1u)) >> 16;
}

// ---------------------------------------------------------------------------
// Kernel 0: WbT[c][d] = bf16(W[d][c])  (transpose-convert, 256x256)
// ---------------------------------------------------------------------------
__global__ __launch_bounds__(256) void wcvt(const float* __restrict__ Wm,
                                            unsigned short* __restrict__ WbT) {
    const int t = threadIdx.x;
    const int c = blockIdx.x * 4 + (t >> 6);
    const int d0 = (t & 63) * 4;
    const float v0 = Wm[(size_t)(d0 + 0) * HFsz + c];
    const float v1 = Wm[(size_t)(d0 + 1) * HFsz + c];
    const float v2 = Wm[(size_t)(d0 + 2) * HFsz + c];
    const float v3 = Wm[(size_t)(d0 + 3) * HFsz + c];
    uint2 pk;
    pk.x = f2bf(v0) | (f2bf(v1) << 16);
    pk.y = f2bf(v2) | (f2bf(v3) << 16);
    *(uint2*)&WbT[(size_t)c * Dsz + d0] = pk;   // coalesced 512B/wave
}

// ---------------------------------------------------------------------------
// Kernel 0.5: adj -> bitmask, tile-major layout.
// adjM byte address: (r>>4)*2048 + (j8>>3)*128 + (r&15)*8 + (j8&7)
//   where r = b*1024+i, j8 = j>>3, bit w of byte = (adj[r][j8*8+w] > 0.5).
// => for a 16-row i-tile and 64-col j-tile, the 16 uint64 row-masks are
//    CONTIGUOUS 128 B at ((b*64+it)*16 + jt)*128 -> one s_load burst in attn.
// Pure streaming pass: 64 MB read / 2 MB write, latency-irrelevant.
// ---------------------------------------------------------------------------
__global__ __launch_bounds__(256) void adjbin(const float* __restrict__ adj,
                                              unsigned char* __restrict__ adjM) {
    const int wg = (blockIdx.x * 256 + threadIdx.x) >> 6;   // wave id [0,2048)
    const int lane = threadIdx.x & 63;
#pragma unroll 1
    for (int s = wg; s < 32768; s += 2048) {                // 2 spans x 16384 rows
        const int r = s >> 1, c0 = (s & 1) * 512;
        const float4* src = (const float4*)(adj + (size_t)r * 1024 + c0 + lane * 8);
        const float4 a0 = src[0], a1 = src[1];              // 2 KB/wave, coalesced
        unsigned by = 0;
        by |= (a0.x > 0.5f) ? 1u : 0u;
        by |= (a0.y > 0.5f) ? 2u : 0u;
        by |= (a0.z > 0.5f) ? 4u : 0u;
        by |= (a0.w > 0.5f) ? 8u : 0u;
        by |= (a1.x > 0.5f) ? 16u : 0u;
        by |= (a1.y > 0.5f) ? 32u : 0u;
        by |= (a1.z > 0.5f) ? 64u : 0u;
        by |= (a1.w > 0.5f) ? 128u : 0u;
        const int j8 = (s & 1) * 64 + lane;
        adjM[(size_t)(r >> 4) * 2048 + (j8 >> 3) * 128 + (r & 15) * 8 + (j8 & 7)] =
            (unsigned char)by;
    }
}

// ---------------------------------------------------------------------------
// Kernel 1: hT = bf16(x @ W)^T via MFMA + fused e_src/e_dst (fp32 dots).
// e_src/e_dst stored PRE-SCALED by log2(e). (unchanged, verified)
// ---------------------------------------------------------------------------
__global__ __launch_bounds__(256) void gat_h_e3(
    const float* __restrict__ x,              // [BN][D]
    const unsigned short* __restrict__ WbT,   // [HF][D] bf16
    const float* __restrict__ a_src,          // [HF]
    const float* __restrict__ a_dst,          // [HF]
    unsigned short* __restrict__ hT,          // [B][HF][N] bf16
    float* __restrict__ esrcT,                // [B][H][N]  (x log2e)
    float* __restrict__ edstT)                // [B][H][N]  (x log2e)
{
    const int n0g = blockIdx.x * 32, b = n0g >> 10, n0 = n0g & 1023;
    const int t = threadIdx.x, lane = t & 63, w = t >> 6;
    const int m = lane & 15, q = lane >> 4;

    __shared__ alignas(16) unsigned short Lds[4 * 64 * 40];  // 10240 hw = 20 KB

    const float4* x4 = (const float4*)(x + (size_t)n0g * Dsz);
#pragma unroll
    for (int i = 0; i < 8; ++i) {
        const int f = t + 256 * i;
        const int row = f >> 6, d4 = (f & 63) * 4;
        const float4 xv = x4[f];
        uint2 pk;
        pk.x = f2bf(xv.x) | (f2bf(xv.y) << 16);
        pk.y = f2bf(xv.z) | (f2bf(xv.w) << 16);
        *(uint2*)&Lds[row * 264 + d4] = pk;
    }
    __syncthreads();

    const unsigned short* Ab = WbT + (size_t)(w * 64 + m) * Dsz + q * 8;
    f32x4 acc[4][2];
#pragma unroll
    for (int ht = 0; ht < 4; ++ht)
#pragma unroll
        for (int nt = 0; nt < 2; ++nt) acc[ht][nt] = (f32x4){0.f, 0.f, 0.f, 0.f};

#pragma unroll
    for (int kk = 0; kk < 8; ++kk) {
        const int k0 = kk * 32;
        const bf16x8 bfr0 = *(const bf16x8*)&Lds[(0 * 16 + m) * 264 + k0 + q * 8];
        const bf16x8 bfr1 = *(const bf16x8*)&Lds[(1 * 16 + m) * 264 + k0 + q * 8];
#pragma unroll
        for (int ht = 0; ht < 4; ++ht) {
            const bf16x8 afr = *(const bf16x8*)&Ab[ht * 16 * Dsz + k0];
            acc[ht][0] = __builtin_amdgcn_mfma_f32_16x16x32_bf16(afr, bfr0, acc[ht][0], 0, 0, 0);
            acc[ht][1] = __builtin_amdgcn_mfma_f32_16x16x32_bf16(afr, bfr1, acc[ht][1], 0, 0, 0);
        }
    }

    float ps0 = 0.f, ps1 = 0.f, pd0 = 0.f, pd1 = 0.f;
#pragma unroll
    for (int ht = 0; ht < 4; ++ht)
#pragma unroll
        for (int r = 0; r < 4; ++r) {
            const float as = a_src[w * 64 + ht * 16 + q * 4 + r];
            const float ad = a_dst[w * 64 + ht * 16 + q * 4 + r];
            ps0 += acc[ht][0][r] * as;  ps1 += acc[ht][1][r] * as;
            pd0 += acc[ht][0][r] * ad;  pd1 += acc[ht][1][r] * ad;
        }
    ps0 += __shfl_xor(ps0, 16, 64); ps0 += __shfl_xor(ps0, 32, 64);
    ps1 += __shfl_xor(ps1, 16, 64); ps1 += __shfl_xor(ps1, 32, 64);
    pd0 += __shfl_xor(pd0, 16, 64); pd0 += __shfl_xor(pd0, 32, 64);
    pd1 += __shfl_xor(pd1, 16, 64); pd1 += __shfl_xor(pd1, 32, 64);
    if (q == 0) {
        const size_t eb = (size_t)(b * Hsz + w) * Nsz + n0;
        esrcT[eb + m]      = ps0 * LOG2E;  esrcT[eb + 16 + m] = ps1 * LOG2E;
        edstT[eb + m]      = pd0 * LOG2E;  edstT[eb + 16 + m] = pd1 * LOG2E;
    }

    __syncthreads();   // xs no longer needed; reuse LDS as hs[4][64][40]

#pragma unroll
    for (int ht = 0; ht < 4; ++ht)
#pragma unroll
        for (int r = 0; r < 4; ++r) {
            const int hf = ht * 16 + q * 4 + r;
            Lds[w * 2560 + hf * 40 + m]      = (unsigned short)f2bf(acc[ht][0][r]);
            Lds[w * 2560 + hf * 40 + 16 + m] = (unsigned short)f2bf(acc[ht][1][r]);
        }
#pragma unroll
    for (int s = 0; s < 4; ++s) {
        const int hf = s * 16 + (lane >> 2), ck = lane & 3;
        const bf16x8 hv = *(const bf16x8*)&Lds[w * 2560 + hf * 40 + ck * 8];
        *(bf16x8*)&hT[(size_t)(b * HFsz + w * 64 + hf) * Nsz + n0 + ck * 8] = hv;
    }
}

// ---------------------------------------------------------------------------
// Kernel 2 (v8): barrier-free main loop + SGPR bitmasks + 2-wave j-split.
// R7 post-mortem: v7's 16 barriers/loop serialized all 8 waves (VALU 19%,
// pre-registered signature). v8 returns to v4's proven barrier-free wave
// structure and removes adj from the critical path ENTIRELY: masks come from
// the 2 MB L2-resident adjM (tile's 16 row-masks = contiguous 128 B, loaded
// wave-uniform via readfirstlane(jt) -> s_load into SGPRs). Masking is one
// v_cndmask_b32 with SGPR-pair selector (bit=lane=j, v4 P-layout). ed is
// SGPR-resident (readfirstlane). es: 1-reg ping-pong prefetch. bfr (hT,
// L2-hot) issues before the exp chain to self-hide. 4096 blocks x 128 thr
// (2 waves = j-halves), launch_bounds(128,6) -> 24 waves/CU, est ~84 regs.
// One barrier total (epilogue comb, harness-verified v5 mapping, j2 over 2).
// ---------------------------------------------------------------------------
__global__ __launch_bounds__(128, 6) void gat_attn8(
    const unsigned char* __restrict__ adjM, // [B][64][16][128B] bit-tiles
    const unsigned short* __restrict__ hT,  // [B][HF][N] bf16
    const float* __restrict__ esrcT,        // [B][H][N] (x log2e)
    const float* __restrict__ edstT,        // [B][H][N] (x log2e)
    const float* __restrict__ bias,         // [HF]
    float* __restrict__ outp)               // [BN][HF]
{
    const int gid = blockIdx.x;
    const int b  = gid & 15;                 // xcd = gid%8 -> b%8 (L2 locality)
    const int hw = (gid >> 4) & 3;           // head
    const int it = gid >> 6, i0 = it * 16;
    const int t = threadIdx.x;
    const int lane = t & 63, jh = t >> 6;    // jh = j-half (2 waves)
    const int m = lane & 15, q = lane >> 4;

    // [0,4608): 2 wave-private P tiles [16][72] ushort (main loop);
    // epilogue aliases all 10240 B as comb[2][64][20] f32.
    __shared__ alignas(16) float smem[2560];
    unsigned short* Pw = (unsigned short*)smem + jh * 1152;

    const float* esb = esrcT + (size_t)(b * Hsz + hw) * Nsz;
    const float* edb = edstT + (size_t)(b * Hsz + hw) * Nsz + i0;
    const unsigned short* hTb = hT + (size_t)(b * HFsz + hw * 64 + m) * Nsz + q * 8;
    const unsigned long long* mkb =
        (const unsigned long long*)(adjM + (size_t)(b * 64 + it) * 2048);

    // ed for the 16 rows: wave-uniform -> SGPRs
    float edv[16];
#pragma unroll
    for (int il = 0; il < 16; ++il)
        edv[il] = __uint_as_float(
            __builtin_amdgcn_readfirstlane(__float_as_uint(edb[il])));

    bf16x8 ones;                             // denominator row-sum B-frag
#pragma unroll
    for (int i = 0; i < 8; ++i)
        ((unsigned short*)&ones)[i] = 0x3F80;   // bf16 1.0

    f32x4 acc[4];
#pragma unroll
    for (int nt = 0; nt < 4; ++nt) acc[nt] = (f32x4){0.f, 0.f, 0.f, 0.f};
    f32x4 acc5 = (f32x4){0.f, 0.f, 0.f, 0.f};

    const int jt0 = jh * 8;                  // this wave's 8 j-tiles
    float esC = esb[jt0 * 64 + lane];        // prologue es

#pragma unroll 1
    for (int jl = 0; jl < 8; ++jl) {
        const int jt = jt0 + jl;
        const int j0 = jt * 64;
        const int jtu = __builtin_amdgcn_readfirstlane(jt);  // force uniformity

        // (a) issue kk=0 hT loads early (L2 ~200cy, hidden under exp chain)
        bf16x8 bfr0[4], bfr1[4];
#pragma unroll
        for (int nt = 0; nt < 4; ++nt)
            bfr0[nt] = *(const bf16x8*)&hTb[(size_t)nt * 16 * Nsz + j0];

        // (b) es prefetch for next tile (1 reg ping-pong)
        const int jn = (jl < 7) ? (j0 + 64) : j0;
        const float esN = esb[jn + lane];

        // (c) wave-uniform mask loads: contiguous 128 B -> s_load burst
        unsigned long long mk[16];
#pragma unroll
        for (int il = 0; il < 16; ++il) mk[il] = mkb[jtu * 16 + il];

        // (d) exp chain -> wave-private P (bf16 trunc; num/den consistent)
#pragma unroll
        for (int il = 0; il < 16; ++il) {
            float v = edv[il] + esC;          // already x log2e
            v = fmaxf(v, 0.2f * v);           // LeakyReLU (scale>0 commutes)
            float p;
            asm("v_exp_f32 %0, %1" : "=v"(p) : "v"(v));        // 2^v
            unsigned ru;                      // bit lane of mk selects p or 0
            asm("v_cndmask_b32 %0, 0, %1, %2"
                : "=v"(ru) : "v"(p), "s"(mk[il]));
            Pw[il * 72 + lane] = (unsigned short)(ru >> 16);
        }

        // (e) issue kk=1 hT loads (cover under kk0 MFMAs + TLP)
#pragma unroll
        for (int nt = 0; nt < 4; ++nt)
            bfr1[nt] = *(const bf16x8*)&hTb[(size_t)nt * 16 * Nsz + j0 + 32];

        // (f) kk0: in-wave lgkmcnt orders Pw write->read (wave-private)
        {
            const bf16x8 af0 = *(const bf16x8*)&Pw[m * 72 + q * 8];
#pragma unroll
            for (int nt = 0; nt < 4; ++nt)
                acc[nt] = __builtin_amdgcn_mfma_f32_16x16x32_bf16(
                    af0, bfr0[nt], acc[nt], 0, 0, 0);
            acc5 = __builtin_amdgcn_mfma_f32_16x16x32_bf16(af0, ones, acc5, 0, 0, 0);
        }
        // (g) kk1
        {
            const bf16x8 af1 = *(const bf16x8*)&Pw[m * 72 + 32 + q * 8];
#pragma unroll
            for (int nt = 0; nt < 4; ++nt)
                acc[nt] = __builtin_amdgcn_mfma_f32_16x16x32_bf16(
                    af1, bfr1[nt], acc[nt], 0, 0, 0);
            acc5 = __builtin_amdgcn_mfma_f32_16x16x32_bf16(af1, ones, acc5, 0, 0, 0);
        }
        esC = esN;
    }

    // ---- combine the 2 j-half partials (verified v5 mapping, j2 over 2) ----
    __syncthreads();                         // only barrier before epilogue
    {
        float* cw = smem + t * 20;           // (jh*64+lane)*20 == t*20
#pragma unroll
        for (int nt = 0; nt < 4; ++nt)
#pragma unroll
            for (int r = 0; r < 4; ++r) cw[nt * 4 + r] = acc[nt][r];
#pragma unroll
        for (int r = 0; r < 4; ++r) cw[16 + r] = acc5[r];   // den rows q*4+r
    }
    __syncthreads();

#pragma unroll
    for (int u = 0; u < 2; ++u) {
        const int idx = t * 2 + u;               // 256 float4 cells (16x16)
        const int row = idx >> 4, c4 = idx & 15;
        const int rq = row >> 2, rr = row & 3;
        const int nt4 = (c4 >> 2) * 4, mb = (c4 & 3) * 4;
        float n0 = 0.f, n1 = 0.f, n2 = 0.f, n3 = 0.f, den = 0.f;
#pragma unroll
        for (int j2 = 0; j2 < 2; ++j2) {
            const float* cb = smem + (j2 * 64 + rq * 16) * 20;
            den += cb[16 + rr];                  // m=0 copy
            n0 += cb[(mb + 0) * 20 + nt4 + rr];
            n1 += cb[(mb + 1) * 20 + nt4 + rr];
            n2 += cb[(mb + 2) * 20 + nt4 + rr];
            n3 += cb[(mb + 3) * 20 + nt4 + rr];
        }
        const float inv = 1.f / den;
        const float4 b4 = *(const float4*)&bias[hw * 64 + c4 * 4];
        float4 o;
        o.x = n0 * inv + b4.x;  o.y = n1 * inv + b4.y;
        o.z = n2 * inv + b4.z;  o.w = n3 * inv + b4.w;
        *(float4*)&outp[(size_t)(b * Nsz + i0 + row) * HFsz + hw * 64 + c4 * 4] = o;
    }
}

// ---------------------------------------------------------------------------
extern "C" void kernel_launch(void* const* d_in, const int* in_sizes, int n_in,
                              void* d_out, int out_size, void* d_ws, size_t ws_size,
                              hipStream_t stream) {
    const float* x     = (const float*)d_in[0];
    const float* adj   = (const float*)d_in[1];
    const float* Wm    = (const float*)d_in[2];
    const float* a_src = (const float*)d_in[3];
    const float* a_dst = (const float*)d_in[4];
    const float* bias  = (const float*)d_in[5];
    float* outp = (float*)d_out;

    // ws: hT bf16 (8MB) | WbT bf16 (128KB) | esrcT (256KB) | edstT (256KB) | adjM (2MB)
    unsigned short* hT  = (unsigned short*)d_ws;
    unsigned short* WbT = hT + (size_t)BN * HFsz;
    float* esrcT = (float*)(WbT + (size_t)HFsz * Dsz);
    float* edstT = esrcT + (size_t)Bsz * Hsz * Nsz;
    unsigned char* adjM = (unsigned char*)(edstT + (size_t)Bsz * Hsz * Nsz);

    adjbin<<<dim3(512), dim3(256), 0, stream>>>(adj, adjM);
    wcvt<<<dim3(64), dim3(256), 0, stream>>>(Wm, WbT);
    gat_h_e3<<<dim3(BN / 32), dim3(256), 0, stream>>>(x, WbT, a_src, a_dst,
                                                      hT, esrcT, edstT);
    gat_attn8<<<dim3(4096), dim3(128), 0, stream>>>(adjM, hT, esrcT, edstT,
                                                    bias, outp);
}

// Round 10
// 190.326 us; speedup vs baseline: 1.7502x; 1.0093x over previous
//
#include <hip/hip_runtime.h>

typedef __bf16 bf16x8 __attribute__((ext_vector_type(8)));
typedef float f32x4 __attribute__((ext_vector_type(4)));

constexpr int Bsz = 16;
constexpr int Nsz = 1024;
constexpr int Dsz = 256;
constexpr int Hsz = 4;
constexpr int HFsz = 256;
constexpr int BN = Bsz * Nsz;
constexpr float LOG2E = 1.44269504088896340736f;

__device__ __forceinline__ unsigned f2bf(float f) {   // RNE fp32->bf16 (finite in)
    unsigned u = __float_as_uint(f);
    return (u + 0x7FFFu + ((u >> 16) & 1u)) >> 16;
}

// ---------------------------------------------------------------------------
// Kernel 0: WbT[c][d] = bf16(W[d][c])  (transpose-convert, 256x256)
// ---------------------------------------------------------------------------
__global__ __launch_bounds__(256) void wcvt(const float* __restrict__ Wm,
                                            unsigned short* __restrict__ WbT) {
    const int t = threadIdx.x;
    const int c = blockIdx.x * 4 + (t >> 6);
    const int d0 = (t & 63) * 4;
    const float v0 = Wm[(size_t)(d0 + 0) * HFsz + c];
    const float v1 = Wm[(size_t)(d0 + 1) * HFsz + c];
    const float v2 = Wm[(size_t)(d0 + 2) * HFsz + c];
    const float v3 = Wm[(size_t)(d0 + 3) * HFsz + c];
    uint2 pk;
    pk.x = f2bf(v0) | (f2bf(v1) << 16);
    pk.y = f2bf(v2) | (f2bf(v3) << 16);
    *(uint2*)&WbT[(size_t)c * Dsz + d0] = pk;   // coalesced 512B/wave
}

// ---------------------------------------------------------------------------
// Kernel 0.5: adj -> bitmask, tile-major layout.
// adjM byte address: (r>>4)*2048 + (j8>>3)*128 + (r&15)*8 + (j8&7)
//   where r = b*1024+i, j8 = j>>3, bit w of byte = (adj[r][j8*8+w] > 0.5).
// => for a 16-row i-tile and 64-col j-tile, the 16 uint64 row-masks are
//    CONTIGUOUS 128 B at ((b*64+it)*16 + jt)*128 -> one s_load burst in attn.
// Pure streaming pass: 64 MB read / 2 MB write, latency-irrelevant.
// ---------------------------------------------------------------------------
__global__ __launch_bounds__(256) void adjbin(const float* __restrict__ adj,
                                              unsigned char* __restrict__ adjM) {
    const int wg = (blockIdx.x * 256 + threadIdx.x) >> 6;   // wave id [0,2048)
    const int lane = threadIdx.x & 63;
#pragma unroll 1
    for (int s = wg; s < 32768; s += 2048) {                // 2 spans x 16384 rows
        const int r = s >> 1, c0 = (s & 1) * 512;
        const float4* src = (const float4*)(adj + (size_t)r * 1024 + c0 + lane * 8);
        const float4 a0 = src[0], a1 = src[1];              // 2 KB/wave, coalesced
        unsigned by = 0;
        by |= (a0.x > 0.5f) ? 1u : 0u;
        by |= (a0.y > 0.5f) ? 2u : 0u;
        by |= (a0.z > 0.5f) ? 4u : 0u;
        by |= (a0.w > 0.5f) ? 8u : 0u;
        by |= (a1.x > 0.5f) ? 16u : 0u;
        by |= (a1.y > 0.5f) ? 32u : 0u;
        by |= (a1.z > 0.5f) ? 64u : 0u;
        by |= (a1.w > 0.5f) ? 128u : 0u;
        const int j8 = (s & 1) * 64 + lane;
        adjM[(size_t)(r >> 4) * 2048 + (j8 >> 3) * 128 + (r & 15) * 8 + (j8 & 7)] =
            (unsigned char)by;
    }
}

// ---------------------------------------------------------------------------
// Kernel 1: hT = bf16(x @ W)^T via MFMA + fused e_src/e_dst (fp32 dots).
// e_src/e_dst stored PRE-SCALED by log2(e). (unchanged, verified)
// ---------------------------------------------------------------------------
__global__ __launch_bounds__(256) void gat_h_e3(
    const float* __restrict__ x,              // [BN][D]
    const unsigned short* __restrict__ WbT,   // [HF][D] bf16
    const float* __restrict__ a_src,          // [HF]
    const float* __restrict__ a_dst,          // [HF]
    unsigned short* __restrict__ hT,          // [B][HF][N] bf16
    float* __restrict__ esrcT,                // [B][H][N]  (x log2e)
    float* __restrict__ edstT)                // [B][H][N]  (x log2e)
{
    const int n0g = blockIdx.x * 32, b = n0g >> 10, n0 = n0g & 1023;
    const int t = threadIdx.x, lane = t & 63, w = t >> 6;
    const int m = lane & 15, q = lane >> 4;

    __shared__ alignas(16) unsigned short Lds[4 * 64 * 40];  // 10240 hw = 20 KB

    const float4* x4 = (const float4*)(x + (size_t)n0g * Dsz);
#pragma unroll
    for (int i = 0; i < 8; ++i) {
        const int f = t + 256 * i;
        const int row = f >> 6, d4 = (f & 63) * 4;
        const float4 xv = x4[f];
        uint2 pk;
        pk.x = f2bf(xv.x) | (f2bf(xv.y) << 16);
        pk.y = f2bf(xv.z) | (f2bf(xv.w) << 16);
        *(uint2*)&Lds[row * 264 + d4] = pk;
    }
    __syncthreads();

    const unsigned short* Ab = WbT + (size_t)(w * 64 + m) * Dsz + q * 8;
    f32x4 acc[4][2];
#pragma unroll
    for (int ht = 0; ht < 4; ++ht)
#pragma unroll
        for (int nt = 0; nt < 2; ++nt) acc[ht][nt] = (f32x4){0.f, 0.f, 0.f, 0.f};

#pragma unroll
    for (int kk = 0; kk < 8; ++kk) {
        const int k0 = kk * 32;
        const bf16x8 bfr0 = *(const bf16x8*)&Lds[(0 * 16 + m) * 264 + k0 + q * 8];
        const bf16x8 bfr1 = *(const bf16x8*)&Lds[(1 * 16 + m) * 264 + k0 + q * 8];
#pragma unroll
        for (int ht = 0; ht < 4; ++ht) {
            const bf16x8 afr = *(const bf16x8*)&Ab[ht * 16 * Dsz + k0];
            acc[ht][0] = __builtin_amdgcn_mfma_f32_16x16x32_bf16(afr, bfr0, acc[ht][0], 0, 0, 0);
            acc[ht][1] = __builtin_amdgcn_mfma_f32_16x16x32_bf16(afr, bfr1, acc[ht][1], 0, 0, 0);
        }
    }

    float ps0 = 0.f, ps1 = 0.f, pd0 = 0.f, pd1 = 0.f;
#pragma unroll
    for (int ht = 0; ht < 4; ++ht)
#pragma unroll
        for (int r = 0; r < 4; ++r) {
            const float as = a_src[w * 64 + ht * 16 + q * 4 + r];
            const float ad = a_dst[w * 64 + ht * 16 + q * 4 + r];
            ps0 += acc[ht][0][r] * as;  ps1 += acc[ht][1][r] * as;
            pd0 += acc[ht][0][r] * ad;  pd1 += acc[ht][1][r] * ad;
        }
    ps0 += __shfl_xor(ps0, 16, 64); ps0 += __shfl_xor(ps0, 32, 64);
    ps1 += __shfl_xor(ps1, 16, 64); ps1 += __shfl_xor(ps1, 32, 64);
    pd0 += __shfl_xor(pd0, 16, 64); pd0 += __shfl_xor(pd0, 32, 64);
    pd1 += __shfl_xor(pd1, 16, 64); pd1 += __shfl_xor(pd1, 32, 64);
    if (q == 0) {
        const size_t eb = (size_t)(b * Hsz + w) * Nsz + n0;
        esrcT[eb + m]      = ps0 * LOG2E;  esrcT[eb + 16 + m] = ps1 * LOG2E;
        edstT[eb + m]      = pd0 * LOG2E;  edstT[eb + 16 + m] = pd1 * LOG2E;
    }

    __syncthreads();   // xs no longer needed; reuse LDS as hs[4][64][40]

#pragma unroll
    for (int ht = 0; ht < 4; ++ht)
#pragma unroll
        for (int r = 0; r < 4; ++r) {
            const int hf = ht * 16 + q * 4 + r;
            Lds[w * 2560 + hf * 40 + m]      = (unsigned short)f2bf(acc[ht][0][r]);
            Lds[w * 2560 + hf * 40 + 16 + m] = (unsigned short)f2bf(acc[ht][1][r]);
        }
#pragma unroll
    for (int s = 0; s < 4; ++s) {
        const int hf = s * 16 + (lane >> 2), ck = lane & 3;
        const bf16x8 hv = *(const bf16x8*)&Lds[w * 2560 + hf * 40 + ck * 8];
        *(bf16x8*)&hT[(size_t)(b * HFsz + w * 64 + hf) * Nsz + n0 + ck * 8] = hv;
    }
}

// ---------------------------------------------------------------------------
// Kernel 2 (v9): v8 + full occupancy (launch_bounds(128,8)).
// R9 post-mortem: v8 = 67us, FETCH 6.5MB (bitmask worked), but VALU 19% /
// MFMA 5.7% -- still latency-bound. Budget check: 16 blocks/CU of work vs
// 12 resident at (128,6) -> a 4-block tail generation at 33% occupancy and
// never-full packing. Resources allow 16 blocks/CU: VGPR 32 (+~20 AGPR) <=
// 64-reg cap @ 8 waves/SIMD; SGPR 64 ok; LDS 10240 B x 16 = exactly 160 KiB.
// (128,8) -> 32 waves/CU, single generation, zero tail. One variable changed
// vs v8 for clean attribution. Mask SGPR-prefetch deliberately NOT added
// (+32 SGPR would risk the per-SIMD SGPR pool at 8 waves).
// ---------------------------------------------------------------------------
__global__ __launch_bounds__(128, 8) void gat_attn8(
    const unsigned char* __restrict__ adjM, // [B][64][16][128B] bit-tiles
    const unsigned short* __restrict__ hT,  // [B][HF][N] bf16
    const float* __restrict__ esrcT,        // [B][H][N] (x log2e)
    const float* __restrict__ edstT,        // [B][H][N] (x log2e)
    const float* __restrict__ bias,         // [HF]
    float* __restrict__ outp)               // [BN][HF]
{
    const int gid = blockIdx.x;
    const int b  = gid & 15;                 // xcd = gid%8 -> b%8 (L2 locality)
    const int hw = (gid >> 4) & 3;           // head
    const int it = gid >> 6, i0 = it * 16;
    const int t = threadIdx.x;
    const int lane = t & 63, jh = t >> 6;    // jh = j-half (2 waves)
    const int m = lane & 15, q = lane >> 4;

    // [0,4608): 2 wave-private P tiles [16][72] ushort (main loop);
    // epilogue aliases all 10240 B as comb[2][64][20] f32.
    __shared__ alignas(16) float smem[2560];
    unsigned short* Pw = (unsigned short*)smem + jh * 1152;

    const float* esb = esrcT + (size_t)(b * Hsz + hw) * Nsz;
    const float* edb = edstT + (size_t)(b * Hsz + hw) * Nsz + i0;
    const unsigned short* hTb = hT + (size_t)(b * HFsz + hw * 64 + m) * Nsz + q * 8;
    const unsigned long long* mkb =
        (const unsigned long long*)(adjM + (size_t)(b * 64 + it) * 2048);

    // ed for the 16 rows: wave-uniform -> SGPRs
    float edv[16];
#pragma unroll
    for (int il = 0; il < 16; ++il)
        edv[il] = __uint_as_float(
            __builtin_amdgcn_readfirstlane(__float_as_uint(edb[il])));

    bf16x8 ones;                             // denominator row-sum B-frag
#pragma unroll
    for (int i = 0; i < 8; ++i)
        ((unsigned short*)&ones)[i] = 0x3F80;   // bf16 1.0

    f32x4 acc[4];
#pragma unroll
    for (int nt = 0; nt < 4; ++nt) acc[nt] = (f32x4){0.f, 0.f, 0.f, 0.f};
    f32x4 acc5 = (f32x4){0.f, 0.f, 0.f, 0.f};

    const int jt0 = jh * 8;                  // this wave's 8 j-tiles
    float esC = esb[jt0 * 64 + lane];        // prologue es

#pragma unroll 1
    for (int jl = 0; jl < 8; ++jl) {
        const int jt = jt0 + jl;
        const int j0 = jt * 64;
        const int jtu = __builtin_amdgcn_readfirstlane(jt);  // force uniformity

        // (a) issue kk=0 hT loads early (L2 ~200cy, hidden under exp chain)
        bf16x8 bfr0[4], bfr1[4];
#pragma unroll
        for (int nt = 0; nt < 4; ++nt)
            bfr0[nt] = *(const bf16x8*)&hTb[(size_t)nt * 16 * Nsz + j0];

        // (b) es prefetch for next tile (1 reg ping-pong)
        const int jn = (jl < 7) ? (j0 + 64) : j0;
        const float esN = esb[jn + lane];

        // (c) wave-uniform mask loads: contiguous 128 B -> s_load burst
        unsigned long long mk[16];
#pragma unroll
        for (int il = 0; il < 16; ++il) mk[il] = mkb[jtu * 16 + il];

        // (d) exp chain -> wave-private P (bf16 trunc; num/den consistent)
#pragma unroll
        for (int il = 0; il < 16; ++il) {
            float v = edv[il] + esC;          // already x log2e
            v = fmaxf(v, 0.2f * v);           // LeakyReLU (scale>0 commutes)
            float p;
            asm("v_exp_f32 %0, %1" : "=v"(p) : "v"(v));        // 2^v
            unsigned ru;                      // bit lane of mk selects p or 0
            asm("v_cndmask_b32 %0, 0, %1, %2"
                : "=v"(ru) : "v"(p), "s"(mk[il]));
            Pw[il * 72 + lane] = (unsigned short)(ru >> 16);
        }

        // (e) issue kk=1 hT loads (cover under kk0 MFMAs + TLP)
#pragma unroll
        for (int nt = 0; nt < 4; ++nt)
            bfr1[nt] = *(const bf16x8*)&hTb[(size_t)nt * 16 * Nsz + j0 + 32];

        // (f) kk0: in-wave lgkmcnt orders Pw write->read (wave-private)
        {
            const bf16x8 af0 = *(const bf16x8*)&Pw[m * 72 + q * 8];
#pragma unroll
            for (int nt = 0; nt < 4; ++nt)
                acc[nt] = __builtin_amdgcn_mfma_f32_16x16x32_bf16(
                    af0, bfr0[nt], acc[nt], 0, 0, 0);
            acc5 = __builtin_amdgcn_mfma_f32_16x16x32_bf16(af0, ones, acc5, 0, 0, 0);
        }
        // (g) kk1
        {
            const bf16x8 af1 = *(const bf16x8*)&Pw[m * 72 + 32 + q * 8];
#pragma unroll
            for (int nt = 0; nt < 4; ++nt)
                acc[nt] = __builtin_amdgcn_mfma_f32_16x16x32_bf16(
                    af1, bfr1[nt], acc[nt], 0, 0, 0);
            acc5 = __builtin_amdgcn_mfma_f32_16x16x32_bf16(af1, ones, acc5, 0, 0, 0);
        }
        esC = esN;
    }

    // ---- combine the 2 j-half partials (verified v5 mapping, j2 over 2) ----
    __syncthreads();                         // only barrier before epilogue
    {
        float* cw = smem + t * 20;           // (jh*64+lane)*20 == t*20
#pragma unroll
        for (int nt = 0; nt < 4; ++nt)
#pragma unroll
            for (int r = 0; r < 4; ++r) cw[nt * 4 + r] = acc[nt][r];
#pragma unroll
        for (int r = 0; r < 4; ++r) cw[16 + r] = acc5[r];   // den rows q*4+r
    }
    __syncthreads();

#pragma unroll
    for (int u = 0; u < 2; ++u) {
        const int idx = t * 2 + u;               // 256 float4 cells (16x16)
        const int row = idx >> 4, c4 = idx & 15;
        const int rq = row >> 2, rr = row & 3;
        const int nt4 = (c4 >> 2) * 4, mb = (c4 & 3) * 4;
        float n0 = 0.f, n1 = 0.f, n2 = 0.f, n3 = 0.f, den = 0.f;
#pragma unroll
        for (int j2 = 0; j2 < 2; ++j2) {
            const float* cb = smem + (j2 * 64 + rq * 16) * 20;
            den += cb[16 + rr];                  // m=0 copy
            n0 += cb[(mb + 0) * 20 + nt4 + rr];
            n1 += cb[(mb + 1) * 20 + nt4 + rr];
            n2 += cb[(mb + 2) * 20 + nt4 + rr];
            n3 += cb[(mb + 3) * 20 + nt4 + rr];
        }
        const float inv = 1.f / den;
        const float4 b4 = *(const float4*)&bias[hw * 64 + c4 * 4];
        float4 o;
        o.x = n0 * inv + b4.x;  o.y = n1 * inv + b4.y;
        o.z = n2 * inv + b4.z;  o.w = n3 * inv + b4.w;
        *(float4*)&outp[(size_t)(b * Nsz + i0 + row) * HFsz + hw * 64 + c4 * 4] = o;
    }
}

// ---------------------------------------------------------------------------
extern "C" void kernel_launch(void* const* d_in, const int* in_sizes, int n_in,
                              void* d_out, int out_size, void* d_ws, size_t ws_size,
                              hipStream_t stream) {
    const float* x     = (const float*)d_in[0];
    const float* adj   = (const float*)d_in[1];
    const float* Wm    = (const float*)d_in[2];
    const float* a_src = (const float*)d_in[3];
    const float* a_dst = (const float*)d_in[4];
    const float* bias  = (const float*)d_in[5];
    float* outp = (float*)d_out;

    // ws: hT bf16 (8MB) | WbT bf16 (128KB) | esrcT (256KB) | edstT (256KB) | adjM (2MB)
    unsigned short* hT  = (unsigned short*)d_ws;
    unsigned short* WbT = hT + (size_t)BN * HFsz;
    float* esrcT = (float*)(WbT + (size_t)HFsz * Dsz);
    float* edstT = esrcT + (size_t)Bsz * Hsz * Nsz;
    unsigned char* adjM = (unsigned char*)(edstT + (size_t)Bsz * Hsz * Nsz);

    adjbin<<<dim3(512), dim3(256), 0, stream>>>(adj, adjM);
    wcvt<<<dim3(64), dim3(256), 0, stream>>>(Wm, WbT);
    gat_h_e3<<<dim3(BN / 32), dim3(256), 0, stream>>>(x, WbT, a_src, a_dst,
                                                      hT, esrcT, edstT);
    gat_attn8<<<dim3(4096), dim3(128), 0, stream>>>(adjM, hT, esrcT, edstT,
                                                    bias, outp);
}